// Round 3
// baseline (571.039 us; speedup 1.0000x reference)
//
#include <hip/hip_runtime.h>
#include <hip/hip_bf16.h>
#include <cstdio>

// LoRALinear: out[M,N] = x[M,K] @ W[N,K]^T + bias, W = base + (16/8)*(lora_B @ lora_A)
// M=8192, N=4096, K=4096 (fp32 in/out; internal bf16 MFMA).
// R3: 32x32x16 MFMA (halve MFMA instr count, 2495-TF-class pipe), keep XOR-swizzled LDS.

using bf16   = __bf16;
using bf16x4 = __attribute__((ext_vector_type(4))) __bf16;
using bf16x8 = __attribute__((ext_vector_type(8))) __bf16;
using f32x16 = __attribute__((ext_vector_type(16))) float;

#define TM 128
#define TN 128
#define BK 64

// ---------------- kernel 1: fused prep ----------------
__global__ void prep(const float* __restrict__ x, const float* __restrict__ base,
                     const float* __restrict__ A, const float* __restrict__ B,
                     bf16* __restrict__ Xb, bf16* __restrict__ Wb,
                     long n4x, int K, int rank, float scale, int kshift) {
    const long tid = blockIdx.x * (long)blockDim.x + threadIdx.x;
    if (tid < n4x) {
        const float4 v = reinterpret_cast<const float4*>(x)[tid];
        bf16x4 o;
        o[0] = (bf16)v.x; o[1] = (bf16)v.y; o[2] = (bf16)v.z; o[3] = (bf16)v.w;
        reinterpret_cast<bf16x4*>(Xb)[tid] = o;
    } else {
        const long t  = tid - n4x;
        const int  o  = (int)(t >> kshift);
        const int  i0 = (int)(t & ((1L << kshift) - 1)) * 4;
        float4 acc = make_float4(0.f, 0.f, 0.f, 0.f);
        for (int r = 0; r < rank; ++r) {
            const float br = B[(size_t)o * rank + r];
            const float4 av = *reinterpret_cast<const float4*>(A + (size_t)r * K + i0);
            acc.x += br * av.x; acc.y += br * av.y; acc.z += br * av.z; acc.w += br * av.w;
        }
        const float4 bb = *reinterpret_cast<const float4*>(base + (size_t)o * K + i0);
        bf16x4 ov;
        ov[0] = (bf16)(bb.x + scale * acc.x);
        ov[1] = (bf16)(bb.y + scale * acc.y);
        ov[2] = (bf16)(bb.z + scale * acc.z);
        ov[3] = (bf16)(bb.w + scale * acc.w);
        *reinterpret_cast<bf16x4*>(Wb + (size_t)o * K + i0) = ov;
    }
}

// ---------------- kernel 2: bf16 GEMM, C = X @ W^T + bias ----------------
// 128x128 block, 4 waves in 2x2, each wave 64x64 = 2x2 blocks of 32x32x16 MFMA.
// LDS tile 128 rows x 8 chunks (16B); global chunk (row,c8) stored at (row, c8^(row&7)).
// A-frag: m=lane&31, k=(lane>>5)*8+j. C/D: col=lane&31, row=(reg&3)+8*(reg>>2)+4*(lane>>5).
__global__ __launch_bounds__(256) void gemm_bt_bf16(
    const bf16* __restrict__ Xb,    // [M,K] row-major
    const bf16* __restrict__ Wb,    // [N,K] row-major
    const float* __restrict__ bias, // [N]
    float* __restrict__ out,        // [M,N] row-major fp32
    int M, int N, int K)
{
    __shared__ __align__(16) bf16 As[TM * BK];
    __shared__ __align__(16) bf16 Bs[TN * BK];

    const int tid  = threadIdx.x;
    const int lane = tid & 63;
    const int wv   = tid >> 6;        // wave 0..3
    const int wm   = wv >> 1;         // 2x2 wave grid
    const int wn   = wv & 1;
    const int m0   = blockIdx.y * TM;
    const int n0   = blockIdx.x * TN;

    const int r32   = lane & 31;      // A/B frag row; C/D col
    const int halfk = lane >> 5;      // selects k half (0..7 vs 8..15)
    const int xv    = r32 & 7;        // XOR swizzle for fragment reads

    // Staging source swizzle: lane covers LDS chunk grp*64+lane.
    const int srow = lane >> 3;                     // row offset within 8-row group
    const int scol = ((lane & 7) ^ (srow & 7)) * 8; // swizzled global column (elems)

    f32x16 acc[2][2] = {};

    for (int k0 = 0; k0 < K; k0 += BK) {
#pragma unroll
        for (int i = 0; i < 4; ++i) {
            const int grp = i * 4 + wv;             // 0..15 (wave-uniform)
            const int row = grp * 8 + srow;         // tile row 0..127
            const bf16* ga = Xb + (size_t)(m0 + row) * K + k0 + scol;
            const bf16* gb = Wb + (size_t)(n0 + row) * K + k0 + scol;
            __builtin_amdgcn_global_load_lds(
                (const __attribute__((address_space(1))) void*)ga,
                (__attribute__((address_space(3))) void*)(As + grp * 512),
                16, 0, 0);
            __builtin_amdgcn_global_load_lds(
                (const __attribute__((address_space(1))) void*)gb,
                (__attribute__((address_space(3))) void*)(Bs + grp * 512),
                16, 0, 0);
        }
        __syncthreads();

#pragma unroll
        for (int ks = 0; ks < 4; ++ks) {            // 4 k-steps of 16
            const int kc  = ks * 2 + halfk;         // k-chunk 0..7
            const int off = (kc ^ xv) * 8;          // swizzled element offset in row
            bf16x8 af[2], bfr[2];
#pragma unroll
            for (int t = 0; t < 2; ++t) {
                af[t]  = *reinterpret_cast<const bf16x8*>(&As[(wm * 64 + t * 32 + r32) * BK + off]);
                bfr[t] = *reinterpret_cast<const bf16x8*>(&Bs[(wn * 64 + t * 32 + r32) * BK + off]);
            }
            acc[0][0] = __builtin_amdgcn_mfma_f32_32x32x16_bf16(af[0], bfr[0], acc[0][0], 0, 0, 0);
            acc[0][1] = __builtin_amdgcn_mfma_f32_32x32x16_bf16(af[0], bfr[1], acc[0][1], 0, 0, 0);
            acc[1][0] = __builtin_amdgcn_mfma_f32_32x32x16_bf16(af[1], bfr[0], acc[1][0], 0, 0, 0);
            acc[1][1] = __builtin_amdgcn_mfma_f32_32x32x16_bf16(af[1], bfr[1], acc[1][1], 0, 0, 0);
        }
        __syncthreads();
    }

    // ---- epilogue: add bias; fp32 store ----
#pragma unroll
    for (int mi = 0; mi < 2; ++mi) {
#pragma unroll
        for (int ni = 0; ni < 2; ++ni) {
            const int gc = n0 + wn * 64 + ni * 32 + r32;
            const float bv = bias[gc];
            const int gr0 = m0 + wm * 64 + mi * 32 + 4 * halfk;
#pragma unroll
            for (int reg = 0; reg < 16; ++reg) {
                const int gr = gr0 + (reg & 3) + 8 * (reg >> 2);
                out[(size_t)gr * N + gc] = acc[mi][ni][reg] + bv;
            }
        }
    }
}

extern "C" void kernel_launch(void* const* d_in, const int* in_sizes, int n_in,
                              void* d_out, int out_size, void* d_ws, size_t ws_size,
                              hipStream_t stream) {
    const float* x    = (const float*)d_in[0];
    const float* base = (const float*)d_in[1];
    const float* lA   = (const float*)d_in[2];
    const float* lB   = (const float*)d_in[3];
    const float* bias = (const float*)d_in[4];
    float* out = (float*)d_out;

    const int  N    = in_sizes[4];             // d_out = 4096
    const int  rank = in_sizes[3] / N;         // 8
    const int  K    = in_sizes[2] / rank;      // d_in = 4096
    const long M    = (long)in_sizes[0] / K;   // 8192
    const float scale = 16.0f / (float)rank;   // alpha/rank = 2.0

    bf16* Xb = (bf16*)d_ws;
    bf16* Wb = Xb + (size_t)M * K;
    const size_t need = ((size_t)M * K + (size_t)N * K) * sizeof(bf16);
    if (ws_size < need) {
        fprintf(stderr, "kernel_launch: ws_size %zu < needed %zu\n", ws_size, need);
        return;
    }

    const long n4x = (long)M * K / 4;
    const long n4w = (long)N * K / 4;
    int kshift = 0;
    while ((1L << kshift) < (long)K / 4) ++kshift;  // log2(K/4)
    const long nthreads = n4x + n4w;
    prep<<<dim3((unsigned)((nthreads + 255) / 256)), dim3(256), 0, stream>>>(
        x, base, lA, lB, Xb, Wb, n4x, K, rank, scale, kshift);

    gemm_bt_bf16<<<dim3(N / TN, (unsigned)(M / TM)), dim3(256), 0, stream>>>(
        Xb, Wb, bias, out, (int)M, N, K);
}

// Round 4
// 564.232 us; speedup vs baseline: 1.0121x; 1.0121x over previous
//
#include <hip/hip_runtime.h>
#include <hip/hip_bf16.h>
#include <cstdio>

// LoRALinear: out[M,N] = x[M,K] @ W[N,K]^T + bias, W = base + (16/8)*(lora_B @ lora_A)
// M=8192, N=4096, K=4096 (fp32 in/out; internal bf16 MFMA).
// R4: revert to R2 16x16x32 structure (0 LDS conflicts @ 307us; R3's 32x32 had conflicts
// + issue-idle). New: hoist all k-invariant LDS fragment offsets out of the K-loop and
// strength-reduce global staging pointers (attack VALUBusy=53%).

using bf16   = __bf16;
using bf16x4 = __attribute__((ext_vector_type(4))) __bf16;
using bf16x8 = __attribute__((ext_vector_type(8))) __bf16;
using f32x4  = __attribute__((ext_vector_type(4))) float;

#define TM 128
#define TN 128
#define BK 64

// ---------------- kernel 1: fused prep ----------------
__global__ void prep(const float* __restrict__ x, const float* __restrict__ base,
                     const float* __restrict__ A, const float* __restrict__ B,
                     bf16* __restrict__ Xb, bf16* __restrict__ Wb,
                     long n4x, int K, int rank, float scale, int kshift) {
    const long tid = blockIdx.x * (long)blockDim.x + threadIdx.x;
    if (tid < n4x) {
        const float4 v = reinterpret_cast<const float4*>(x)[tid];
        bf16x4 o;
        o[0] = (bf16)v.x; o[1] = (bf16)v.y; o[2] = (bf16)v.z; o[3] = (bf16)v.w;
        reinterpret_cast<bf16x4*>(Xb)[tid] = o;
    } else {
        const long t  = tid - n4x;
        const int  o  = (int)(t >> kshift);
        const int  i0 = (int)(t & ((1L << kshift) - 1)) * 4;
        float4 acc = make_float4(0.f, 0.f, 0.f, 0.f);
        for (int r = 0; r < rank; ++r) {
            const float br = B[(size_t)o * rank + r];
            const float4 av = *reinterpret_cast<const float4*>(A + (size_t)r * K + i0);
            acc.x += br * av.x; acc.y += br * av.y; acc.z += br * av.z; acc.w += br * av.w;
        }
        const float4 bb = *reinterpret_cast<const float4*>(base + (size_t)o * K + i0);
        bf16x4 ov;
        ov[0] = (bf16)(bb.x + scale * acc.x);
        ov[1] = (bf16)(bb.y + scale * acc.y);
        ov[2] = (bf16)(bb.z + scale * acc.z);
        ov[3] = (bf16)(bb.w + scale * acc.w);
        *reinterpret_cast<bf16x4*>(Wb + (size_t)o * K + i0) = ov;
    }
}

// ---------------- kernel 2: bf16 GEMM, C = X @ W^T + bias, XOR-swizzled LDS ----------------
// LDS tile 128 rows x 8 chunks (16B); global chunk (row,c8) stored at (row, c8^(row&7)).
// 4 waves in 2x2; each wave 4x4 blocks of 16x16x32 MFMA.
__global__ __launch_bounds__(256) void gemm_bt_bf16(
    const bf16* __restrict__ Xb,    // [M,K] row-major
    const bf16* __restrict__ Wb,    // [N,K] row-major
    const float* __restrict__ bias, // [N]
    float* __restrict__ out,        // [M,N] row-major fp32
    int M, int N, int K)
{
    __shared__ __align__(16) bf16 As[TM * BK];
    __shared__ __align__(16) bf16 Bs[TN * BK];

    const int tid  = threadIdx.x;
    const int lane = tid & 63;
    const int wv   = tid >> 6;        // wave 0..3
    const int wm   = wv >> 1;         // 2x2 wave grid over the 128x128 tile
    const int wn   = wv & 1;
    const int m0   = blockIdx.y * TM;
    const int n0   = blockIdx.x * TN;

    const int r16 = lane & 15;        // row-in-16 for A/B frags, col for C/D
    const int q   = lane >> 4;        // quad 0..3
    const int xv  = r16 & 7;          // XOR swizzle value for fragment reads

    // Staging source swizzle: lane covers LDS chunk grp*64+lane.
    const int srow = lane >> 3;                     // row offset within 8-row group
    const int scol = ((lane & 7) ^ (srow & 7)) * 8; // swizzled global column (elems)

    // ---- hoist: global staging pointers (advance by BK per iter) ----
    const bf16* gA[4];
    const bf16* gB[4];
#pragma unroll
    for (int i = 0; i < 4; ++i) {
        const int grp = i * 4 + wv;
        const int row = grp * 8 + srow;
        gA[i] = Xb + (size_t)(m0 + row) * K + scol;
        gB[i] = Wb + (size_t)(n0 + row) * K + scol;
    }

    // ---- hoist: k-invariant LDS fragment offsets (element indices) ----
    int ao[2][4], bo[2][4];
#pragma unroll
    for (int ks = 0; ks < 2; ++ks) {
        const int off = ((ks * 4 + q) ^ xv) * 8;    // swizzled element offset in row
#pragma unroll
        for (int t = 0; t < 4; ++t) {
            ao[ks][t] = (wm * 64 + t * 16 + r16) * BK + off;
            bo[ks][t] = (wn * 64 + t * 16 + r16) * BK + off;
        }
    }

    f32x4 acc[4][4] = {};

    for (int k0 = 0; k0 < K; k0 += BK) {
#pragma unroll
        for (int i = 0; i < 4; ++i) {
            const int grp = i * 4 + wv;             // wave-uniform
            __builtin_amdgcn_global_load_lds(
                (const __attribute__((address_space(1))) void*)gA[i],
                (__attribute__((address_space(3))) void*)(As + grp * 512),
                16, 0, 0);
            __builtin_amdgcn_global_load_lds(
                (const __attribute__((address_space(1))) void*)gB[i],
                (__attribute__((address_space(3))) void*)(Bs + grp * 512),
                16, 0, 0);
            gA[i] += BK;
            gB[i] += BK;
        }
        __syncthreads();

#pragma unroll
        for (int ks = 0; ks < 2; ++ks) {
            bf16x8 afrag[4], bfrag[4];
#pragma unroll
            for (int t = 0; t < 4; ++t) {
                afrag[t] = *reinterpret_cast<const bf16x8*>(&As[ao[ks][t]]);
                bfrag[t] = *reinterpret_cast<const bf16x8*>(&Bs[bo[ks][t]]);
            }
#pragma unroll
            for (int mi = 0; mi < 4; ++mi)
#pragma unroll
                for (int ni = 0; ni < 4; ++ni)
                    acc[mi][ni] = __builtin_amdgcn_mfma_f32_16x16x32_bf16(
                        afrag[mi], bfrag[ni], acc[mi][ni], 0, 0, 0);
        }
        __syncthreads();
    }

    // ---- epilogue: C/D layout col=lane&15, row=q*4+r; add bias; fp32 store ----
#pragma unroll
    for (int mi = 0; mi < 4; ++mi) {
#pragma unroll
        for (int ni = 0; ni < 4; ++ni) {
            const int gr = m0 + wm * 64 + mi * 16 + q * 4;
            const int gc = n0 + wn * 64 + ni * 16 + r16;
            const float bv = bias[gc];
#pragma unroll
            for (int r = 0; r < 4; ++r)
                out[(size_t)(gr + r) * N + gc] = acc[mi][ni][r] + bv;
        }
    }
}

extern "C" void kernel_launch(void* const* d_in, const int* in_sizes, int n_in,
                              void* d_out, int out_size, void* d_ws, size_t ws_size,
                              hipStream_t stream) {
    const float* x    = (const float*)d_in[0];
    const float* base = (const float*)d_in[1];
    const float* lA   = (const float*)d_in[2];
    const float* lB   = (const float*)d_in[3];
    const float* bias = (const float*)d_in[4];
    float* out = (float*)d_out;

    const int  N    = in_sizes[4];             // d_out = 4096
    const int  rank = in_sizes[3] / N;         // 8
    const int  K    = in_sizes[2] / rank;      // d_in = 4096
    const long M    = (long)in_sizes[0] / K;   // 8192
    const float scale = 16.0f / (float)rank;   // alpha/rank = 2.0

    bf16* Xb = (bf16*)d_ws;
    bf16* Wb = Xb + (size_t)M * K;
    const size_t need = ((size_t)M * K + (size_t)N * K) * sizeof(bf16);
    if (ws_size < need) {
        fprintf(stderr, "kernel_launch: ws_size %zu < needed %zu\n", ws_size, need);
        return;
    }

    const long n4x = (long)M * K / 4;
    const long n4w = (long)N * K / 4;
    int kshift = 0;
    while ((1L << kshift) < (long)K / 4) ++kshift;  // log2(K/4)
    const long nthreads = n4x + n4w;
    prep<<<dim3((unsigned)((nthreads + 255) / 256)), dim3(256), 0, stream>>>(
        x, base, lA, lB, Xb, Wb, n4x, K, rank, scale, kshift);

    gemm_bt_bf16<<<dim3(N / TN, (unsigned)(M / TM)), dim3(256), 0, stream>>>(
        Xb, Wb, bias, out, (int)M, N, K);
}